// Round 3
// baseline (610.647 us; speedup 1.0000x reference)
//
#include <hip/hip_runtime.h>
#include <hip/hip_bf16.h>

#define MAXD 64

typedef __attribute__((ext_vector_type(8))) short bf16x8;
typedef __attribute__((ext_vector_type(4))) float f32x4;

__device__ __forceinline__ float blo(unsigned u){ return __uint_as_float(u << 16); }
__device__ __forceinline__ float bhi(unsigned u){ return __uint_as_float(u & 0xffff0000u); }
__device__ __forceinline__ short cvbf(float f){ return (short)__bfloat16_as_ushort(__float2bfloat16(f)); }
__device__ __forceinline__ unsigned pk2(float a, float b){
  unsigned la = (unsigned)__bfloat16_as_ushort(__float2bfloat16(a));
  unsigned lb = (unsigned)__bfloat16_as_ushort(__float2bfloat16(b));
  return la | (lb << 16);
}

// ---------- degree count + ELL scatter ----------
__global__ __launch_bounds__(256) void k_count(const int* __restrict__ src,
                                               const int* __restrict__ dst,
                                               int* __restrict__ cnt,
                                               int* __restrict__ slots, int E){
  int e = blockIdx.x * 256 + threadIdx.x;
  if (e >= E) return;
  int d = dst[e];
  int s = src[e];
  int pos = atomicAdd(&cnt[d], 1);
  if (pos < MAXD) slots[(size_t)d * MAXD + pos] = s;
}

__global__ __launch_bounds__(256) void k_dinv(const int* __restrict__ cnt,
                                              float* __restrict__ dinv, int n){
  int i = blockIdx.x * 256 + threadIdx.x;
  if (i < n) dinv[i] = rsqrtf((float)cnt[i] + 1.0f);
}

// ---------- W transpose + f32->bf16: WT[c*K + k] = bf16(W[k*C + c]) ----------
__global__ __launch_bounds__(256) void k_tr(const float* __restrict__ W,
                                            __hip_bfloat16* __restrict__ WT, int K, int C){
  int i = blockIdx.x * 256 + threadIdx.x;
  if (i >= K * C) return;
  int k = i / C, c = i % C;
  WT[(size_t)c * K + k] = __float2bfloat16(W[i]);
}

// ---------- GEMM: C[M,128] = A[M,K] @ B  (B given as bf16 BT[128][K]), bf16 out, f32 acc ----------
// A is f32 (AF32=true) or bf16 (AF32=false).
// block = 256 threads = 4 waves; tile = 64 rows x 128 cols; mfma_f32_16x16x32_bf16
#define LDP 40   // padded LDS row length (elements): 80B rows keep 16B align, <=2-way banks
template<bool AF32>
__global__ __launch_bounds__(256) void k_gemm(const void* __restrict__ Av,
                                              const __hip_bfloat16* __restrict__ BT,
                                              __hip_bfloat16* __restrict__ C,
                                              int M, int K){
  __shared__ short As[64 * LDP];
  __shared__ short Bs[128 * LDP];
  int t = threadIdx.x;
  int wave = t >> 6, lane = t & 63;
  int rowbase = blockIdx.x * 64;

  f32x4 zero4 = {0.f, 0.f, 0.f, 0.f};
  f32x4 acc[8];
  #pragma unroll
  for (int f = 0; f < 8; ++f) acc[f] = zero4;

  for (int k0 = 0; k0 < K; k0 += 32){
    // stage A tile: 64 rows x 32 k
    {
      int r = t >> 2, p = t & 3;
      int grow = rowbase + r;
      bf16x8 v = {0,0,0,0,0,0,0,0};
      if (grow < M){
        if (AF32){
          const float* ap = (const float*)Av + (size_t)grow * K + k0 + p * 8;
          float4 f0 = *(const float4*)ap;
          float4 f1 = *(const float4*)(ap + 4);
          v[0] = cvbf(f0.x); v[1] = cvbf(f0.y); v[2] = cvbf(f0.z); v[3] = cvbf(f0.w);
          v[4] = cvbf(f1.x); v[5] = cvbf(f1.y); v[6] = cvbf(f1.z); v[7] = cvbf(f1.w);
        } else {
          const __hip_bfloat16* ap = (const __hip_bfloat16*)Av + (size_t)grow * K + k0 + p * 8;
          v = *(const bf16x8*)ap;
        }
      }
      *(bf16x8*)&As[r * LDP + p * 8] = v;
    }
    // stage B tile: 128 cols x 32 k (2 passes of 256 chunks), already bf16
    #pragma unroll
    for (int q = 0; q < 2; ++q){
      int idx = t + q * 256;
      int c = idx >> 2, p = idx & 3;
      bf16x8 v = *(const bf16x8*)&BT[(size_t)c * K + k0 + p * 8];
      *(bf16x8*)&Bs[c * LDP + p * 8] = v;
    }
    __syncthreads();
    int ks = (lane >> 4) * 8;
    bf16x8 afrag = *(const bf16x8*)&As[(wave * 16 + (lane & 15)) * LDP + ks];
    #pragma unroll
    for (int f = 0; f < 8; ++f){
      bf16x8 bfrag = *(const bf16x8*)&Bs[(f * 16 + (lane & 15)) * LDP + ks];
      acc[f] = __builtin_amdgcn_mfma_f32_16x16x32_bf16(afrag, bfrag, acc[f], 0, 0, 0);
    }
    __syncthreads();
  }
  // epilogue: D layout col = lane&15, row = (lane>>4)*4 + r
  int col0 = lane & 15;
  int r0 = wave * 16 + (lane >> 4) * 4;
  #pragma unroll
  for (int f = 0; f < 8; ++f){
    #pragma unroll
    for (int r = 0; r < 4; ++r){
      int grow = rowbase + r0 + r;
      if (grow < M) C[(size_t)grow * 128 + f * 16 + col0] = __float2bfloat16(acc[f][r]);
    }
  }
}

// ---------- conv1 combine: h = relu(agg + dinv^2*hlin + b1), wave per node, 2ch/lane ----------
__global__ __launch_bounds__(256) void k_agg1(const __hip_bfloat16* __restrict__ hlin,
                                              const int* __restrict__ slots,
                                              const int* __restrict__ cnt,
                                              const float* __restrict__ dinv,
                                              const float* __restrict__ b1,
                                              __hip_bfloat16* __restrict__ h, int n){
  int node = blockIdx.x * 4 + (threadIdx.x >> 6);
  if (node >= n) return;
  int lane = threadIdx.x & 63;
  float di = dinv[node];
  int deg = cnt[node]; if (deg > MAXD) deg = MAXD;
  const int* sl = slots + (size_t)node * MAXD;
  float a0 = 0.f, a1 = 0.f;
  for (int k = 0; k < deg; ++k){
    int s = sl[k];
    float coef = di * dinv[s];
    unsigned v = *(const unsigned*)(hlin + (size_t)s * 128 + lane * 2);
    a0 = fmaf(coef, blo(v), a0);
    a1 = fmaf(coef, bhi(v), a1);
  }
  unsigned sv = *(const unsigned*)(hlin + (size_t)node * 128 + lane * 2);
  float d2 = di * di;
  a0 = fmaf(d2, blo(sv), a0);
  a1 = fmaf(d2, bhi(sv), a1);
  float2 bv = *(const float2*)(b1 + lane * 2);
  a0 += bv.x; a1 += bv.y;
  a0 = fmaxf(a0, 0.f); a1 = fmaxf(a1, 0.f);
  *(unsigned*)(h + (size_t)node * 128 + lane * 2) = pk2(a0, a1);
}

// ---------- conv2 combine + reparam: lanes<32 hold mu chans, lanes>=32 hold logvar chans ----------
__global__ __launch_bounds__(256) void k_agg2(const __hip_bfloat16* __restrict__ hml,
                                              const int* __restrict__ slots,
                                              const int* __restrict__ cnt,
                                              const float* __restrict__ dinv,
                                              const float* __restrict__ bmu,
                                              const float* __restrict__ blv,
                                              const float* __restrict__ eps,
                                              float* __restrict__ outz,
                                              float* __restrict__ outmu,
                                              float* __restrict__ outlv, int n){
  int node = blockIdx.x * 4 + (threadIdx.x >> 6);
  if (node >= n) return;
  int lane = threadIdx.x & 63;
  float di = dinv[node];
  int deg = cnt[node]; if (deg > MAXD) deg = MAXD;
  const int* sl = slots + (size_t)node * MAXD;
  float a0 = 0.f, a1 = 0.f;
  for (int k = 0; k < deg; ++k){
    int s = sl[k];
    float coef = di * dinv[s];
    unsigned v = *(const unsigned*)(hml + (size_t)s * 128 + lane * 2);
    a0 = fmaf(coef, blo(v), a0);
    a1 = fmaf(coef, bhi(v), a1);
  }
  unsigned sv = *(const unsigned*)(hml + (size_t)node * 128 + lane * 2);
  float d2 = di * di;
  a0 = fmaf(d2, blo(sv), a0);
  a1 = fmaf(d2, bhi(sv), a1);
  float2 bv;
  if (lane < 32) bv = *(const float2*)(bmu + lane * 2);
  else           bv = *(const float2*)(blv + (lane - 32) * 2);
  a0 += bv.x; a1 += bv.y;
  // exchange: lane l <-> lane l^32  (mu lane gets logvar of same channels)
  float p0 = __shfl_xor(a0, 32);
  float p1 = __shfl_xor(a1, 32);
  if (lane < 32){
    float2 ev = *(const float2*)(eps + (size_t)node * 64 + lane * 2);
    float z0 = fmaf(ev.x, expf(0.5f * p0), a0);
    float z1 = fmaf(ev.y, expf(0.5f * p1), a1);
    *(float2*)(outz  + (size_t)node * 64 + lane * 2) = make_float2(z0, z1);
    *(float2*)(outmu + (size_t)node * 64 + lane * 2) = make_float2(a0, a1);
  } else {
    int l2 = lane - 32;
    *(float2*)(outlv + (size_t)node * 64 + l2 * 2) = make_float2(a0, a1);
  }
}

// ---------- decoder: 16 lanes per edge, 4 ch each, shfl reduce, sigmoid ----------
__global__ __launch_bounds__(256) void k_dec(const int* __restrict__ src,
                                             const int* __restrict__ dst,
                                             const float* __restrict__ z,
                                             float* __restrict__ dec, int E){
  int t = blockIdx.x * 256 + threadIdx.x;
  int e = t >> 4;
  if (e >= E) return;
  int sl = t & 15;
  int s = src[e], d = dst[e];
  float4 a = *(const float4*)(z + (size_t)s * 64 + sl * 4);
  float4 b = *(const float4*)(z + (size_t)d * 64 + sl * 4);
  float dot = a.x * b.x + a.y * b.y + a.z * b.z + a.w * b.w;
  dot += __shfl_xor(dot, 1);
  dot += __shfl_xor(dot, 2);
  dot += __shfl_xor(dot, 4);
  dot += __shfl_xor(dot, 8);
  if (sl == 0) dec[e] = 1.f / (1.f + expf(-dot));
}

extern "C" void kernel_launch(void* const* d_in, const int* in_sizes, int n_in,
                              void* d_out, int out_size, void* d_ws, size_t ws_size,
                              hipStream_t stream){
  const float* x   = (const float*)d_in[0];
  const int*   ei  = (const int*)d_in[1];
  const float* eps = (const float*)d_in[2];
  const float* W1  = (const float*)d_in[3];
  const float* b1  = (const float*)d_in[4];
  const float* Wmu = (const float*)d_in[5];
  const float* bmu = (const float*)d_in[6];
  const float* Wlv = (const float*)d_in[7];
  const float* blv = (const float*)d_in[8];

  int N = in_sizes[0] / 256;
  int E = in_sizes[1] / 2;
  const int* src = ei;
  const int* dst = ei + E;

  char* w = (char*)d_ws;
  auto alloc = [&](size_t bytes) -> char* {
    char* p = w; w += (bytes + 255) & ~(size_t)255; return p;
  };
  int*            cnt   = (int*)            alloc((size_t)N * 4);
  float*          dinv  = (float*)          alloc((size_t)N * 4);
  int*            slots = (int*)            alloc((size_t)N * MAXD * 4);
  __hip_bfloat16* hlin  = (__hip_bfloat16*) alloc((size_t)N * 128 * 2);  // reused as hmulv
  __hip_bfloat16* h     = (__hip_bfloat16*) alloc((size_t)N * 128 * 2);
  __hip_bfloat16* W1T   = (__hip_bfloat16*) alloc((size_t)256 * 128 * 2);
  __hip_bfloat16* WcT   = (__hip_bfloat16*) alloc((size_t)128 * 128 * 2);

  float* oz   = (float*)d_out;
  float* omu  = oz  + (size_t)N * 64;
  float* olv  = omu + (size_t)N * 64;
  float* odec = olv + (size_t)N * 64;

  (void)hipMemsetAsync(cnt, 0, (size_t)N * 4, stream);

  k_count<<<(E + 255) / 256, 256, 0, stream>>>(src, dst, cnt, slots, E);
  k_dinv<<<(N + 255) / 256, 256, 0, stream>>>(cnt, dinv, N);

  k_tr<<<(256 * 128 + 255) / 256, 256, 0, stream>>>(W1, W1T, 256, 128);
  k_tr<<<(128 * 64 + 255) / 256, 256, 0, stream>>>(Wmu, WcT, 128, 64);
  k_tr<<<(128 * 64 + 255) / 256, 256, 0, stream>>>(Wlv, WcT + (size_t)64 * 128, 128, 64);

  // hlin = x @ W1   [N,128]
  k_gemm<true><<<(N + 63) / 64, 256, 0, stream>>>(x, W1T, hlin, N, 256);
  // h = relu(conv1 combine)
  k_agg1<<<(N + 3) / 4, 256, 0, stream>>>(hlin, slots, cnt, dinv, b1, h, N);
  // hmulv = h @ [Wmu | Wlv]   [N,128]  (reuse hlin buffer)
  k_gemm<false><<<(N + 63) / 64, 256, 0, stream>>>(h, WcT, hlin, N, 128);
  // conv2 combine + reparameterization -> z, mu, logvar
  k_agg2<<<(N + 3) / 4, 256, 0, stream>>>(hlin, slots, cnt, dinv, bmu, blv, eps,
                                          oz, omu, olv, N);
  // decoder on edges
  k_dec<<<(E * 16 + 255) / 256, 256, 0, stream>>>(src, dst, oz, odec, E);
}

// Round 4
// 419.357 us; speedup vs baseline: 1.4562x; 1.4562x over previous
//
#include <hip/hip_runtime.h>
#include <hip/hip_bf16.h>

#define MAXD 64

typedef __attribute__((ext_vector_type(8))) short bf16x8;
typedef __attribute__((ext_vector_type(4))) float f32x4;

__device__ __forceinline__ float blo(unsigned u){ return __uint_as_float(u << 16); }
__device__ __forceinline__ float bhi(unsigned u){ return __uint_as_float(u & 0xffff0000u); }
__device__ __forceinline__ short cvbf(float f){ return (short)__bfloat16_as_ushort(__float2bfloat16(f)); }
__device__ __forceinline__ unsigned pk2(float a, float b){
  unsigned la = (unsigned)__bfloat16_as_ushort(__float2bfloat16(a));
  unsigned lb = (unsigned)__bfloat16_as_ushort(__float2bfloat16(b));
  return la | (lb << 16);
}

// ---------- degree count + ELL scatter ----------
__global__ __launch_bounds__(256) void k_count(const int* __restrict__ src,
                                               const int* __restrict__ dst,
                                               int* __restrict__ cnt,
                                               int* __restrict__ slots, int E){
  int e = blockIdx.x * 256 + threadIdx.x;
  if (e >= E) return;
  int d = dst[e];
  int s = src[e];
  int pos = atomicAdd(&cnt[d], 1);
  if (pos < MAXD) slots[(size_t)d * MAXD + pos] = s;
}

__global__ __launch_bounds__(256) void k_dinv(const int* __restrict__ cnt,
                                              float* __restrict__ dinv, int n){
  int i = blockIdx.x * 256 + threadIdx.x;
  if (i < n) dinv[i] = rsqrtf((float)cnt[i] + 1.0f);
}

// ---------- W transpose + f32->bf16: WT[c*K + k] = bf16(W[k*C + c]) ----------
__global__ __launch_bounds__(256) void k_tr(const float* __restrict__ W,
                                            __hip_bfloat16* __restrict__ WT, int K, int C){
  int i = blockIdx.x * 256 + threadIdx.x;
  if (i >= K * C) return;
  int k = i / C, c = i % C;
  WT[(size_t)c * K + k] = __float2bfloat16(W[i]);
}

// ---------- GEMM: C[M,128] = A[M,K] @ B  (B given as bf16 BT[128][K]), bf16 out, f32 acc ----------
#define LDP 40
template<bool AF32>
__global__ __launch_bounds__(256) void k_gemm(const void* __restrict__ Av,
                                              const __hip_bfloat16* __restrict__ BT,
                                              __hip_bfloat16* __restrict__ C,
                                              int M, int K){
  __shared__ short As[64 * LDP];
  __shared__ short Bs[128 * LDP];
  int t = threadIdx.x;
  int wave = t >> 6, lane = t & 63;
  int rowbase = blockIdx.x * 64;

  f32x4 zero4 = {0.f, 0.f, 0.f, 0.f};
  f32x4 acc[8];
  #pragma unroll
  for (int f = 0; f < 8; ++f) acc[f] = zero4;

  for (int k0 = 0; k0 < K; k0 += 32){
    {
      int r = t >> 2, p = t & 3;
      int grow = rowbase + r;
      bf16x8 v = {0,0,0,0,0,0,0,0};
      if (grow < M){
        if (AF32){
          const float* ap = (const float*)Av + (size_t)grow * K + k0 + p * 8;
          float4 f0 = *(const float4*)ap;
          float4 f1 = *(const float4*)(ap + 4);
          v[0] = cvbf(f0.x); v[1] = cvbf(f0.y); v[2] = cvbf(f0.z); v[3] = cvbf(f0.w);
          v[4] = cvbf(f1.x); v[5] = cvbf(f1.y); v[6] = cvbf(f1.z); v[7] = cvbf(f1.w);
        } else {
          const __hip_bfloat16* ap = (const __hip_bfloat16*)Av + (size_t)grow * K + k0 + p * 8;
          v = *(const bf16x8*)ap;
        }
      }
      *(bf16x8*)&As[r * LDP + p * 8] = v;
    }
    #pragma unroll
    for (int q = 0; q < 2; ++q){
      int idx = t + q * 256;
      int c = idx >> 2, p = idx & 3;
      bf16x8 v = *(const bf16x8*)&BT[(size_t)c * K + k0 + p * 8];
      *(bf16x8*)&Bs[c * LDP + p * 8] = v;
    }
    __syncthreads();
    int ks = (lane >> 4) * 8;
    bf16x8 afrag = *(const bf16x8*)&As[(wave * 16 + (lane & 15)) * LDP + ks];
    #pragma unroll
    for (int f = 0; f < 8; ++f){
      bf16x8 bfrag = *(const bf16x8*)&Bs[(f * 16 + (lane & 15)) * LDP + ks];
      acc[f] = __builtin_amdgcn_mfma_f32_16x16x32_bf16(afrag, bfrag, acc[f], 0, 0, 0);
    }
    __syncthreads();
  }
  int col0 = lane & 15;
  int r0 = wave * 16 + (lane >> 4) * 4;
  #pragma unroll
  for (int f = 0; f < 8; ++f){
    #pragma unroll
    for (int r = 0; r < 4; ++r){
      int grow = rowbase + r0 + r;
      if (grow < M) C[(size_t)grow * 128 + f * 16 + col0] = __float2bfloat16(acc[f][r]);
    }
  }
}

// ---------- conv1 combine, wave/node: lane-group g of 16 lanes owns 1 row (uint4 = 8ch),
//            4 rows/instr, 16 rows in flight per iteration ----------
__global__ __launch_bounds__(256) void k_agg1(const __hip_bfloat16* __restrict__ hlin,
                                              const int* __restrict__ slots,
                                              const int* __restrict__ cnt,
                                              const float* __restrict__ dinv,
                                              const float* __restrict__ b1,
                                              __hip_bfloat16* __restrict__ h, int n){
  int node = blockIdx.x * 4 + (threadIdx.x >> 6);
  if (node >= n) return;
  int lane = threadIdx.x & 63;
  int g = lane >> 4, c = lane & 15;
  float di = dinv[node];
  int deg = cnt[node]; if (deg > MAXD) deg = MAXD;

  int s_k = node; float c_k = 0.f;
  if (lane < deg){ s_k = slots[(size_t)node * MAXD + lane]; c_k = di * dinv[s_k]; }

  float a[8] = {0.f,0.f,0.f,0.f,0.f,0.f,0.f,0.f};
  auto acc8 = [&](uint4 v, float f){
    a[0]=fmaf(f,blo(v.x),a[0]); a[1]=fmaf(f,bhi(v.x),a[1]);
    a[2]=fmaf(f,blo(v.y),a[2]); a[3]=fmaf(f,bhi(v.y),a[3]);
    a[4]=fmaf(f,blo(v.z),a[4]); a[5]=fmaf(f,bhi(v.z),a[5]);
    a[6]=fmaf(f,blo(v.w),a[6]); a[7]=fmaf(f,bhi(v.w),a[7]);
  };

  for (int k0 = 0; k0 < deg; k0 += 16){
    int s0=__shfl(s_k,k0+g), s1=__shfl(s_k,k0+4+g), s2=__shfl(s_k,k0+8+g), s3=__shfl(s_k,k0+12+g);
    float f0=__shfl(c_k,k0+g), f1=__shfl(c_k,k0+4+g), f2=__shfl(c_k,k0+8+g), f3=__shfl(c_k,k0+12+g);
    uint4 v0 = *(const uint4*)(hlin + (size_t)s0*128 + c*8);
    uint4 v1 = *(const uint4*)(hlin + (size_t)s1*128 + c*8);
    uint4 v2 = *(const uint4*)(hlin + (size_t)s2*128 + c*8);
    uint4 v3 = *(const uint4*)(hlin + (size_t)s3*128 + c*8);
    acc8(v0,f0); acc8(v1,f1); acc8(v2,f2); acc8(v3,f3);
  }
  #pragma unroll
  for (int j = 0; j < 8; ++j){
    a[j] += __shfl_xor(a[j], 16);
    a[j] += __shfl_xor(a[j], 32);
  }
  uint4 sv = *(const uint4*)(hlin + (size_t)node*128 + c*8);
  acc8(sv, di * di);
  float4 bA = *(const float4*)(b1 + c*8);
  float4 bB = *(const float4*)(b1 + c*8 + 4);
  a[0]+=bA.x; a[1]+=bA.y; a[2]+=bA.z; a[3]+=bA.w;
  a[4]+=bB.x; a[5]+=bB.y; a[6]+=bB.z; a[7]+=bB.w;
  #pragma unroll
  for (int j = 0; j < 8; ++j) a[j] = fmaxf(a[j], 0.f);
  if (g == 0){
    uint4 o;
    o.x = pk2(a[0],a[1]); o.y = pk2(a[2],a[3]);
    o.z = pk2(a[4],a[5]); o.w = pk2(a[6],a[7]);
    *(uint4*)(h + (size_t)node*128 + c*8) = o;
  }
}

// ---------- conv2 combine + reparam; channel-block c<8 = mu, c>=8 = logvar ----------
__global__ __launch_bounds__(256) void k_agg2(const __hip_bfloat16* __restrict__ hml,
                                              const int* __restrict__ slots,
                                              const int* __restrict__ cnt,
                                              const float* __restrict__ dinv,
                                              const float* __restrict__ bmu,
                                              const float* __restrict__ blv,
                                              const float* __restrict__ eps,
                                              float* __restrict__ outz,
                                              float* __restrict__ outmu,
                                              float* __restrict__ outlv, int n){
  int node = blockIdx.x * 4 + (threadIdx.x >> 6);
  if (node >= n) return;
  int lane = threadIdx.x & 63;
  int g = lane >> 4, c = lane & 15;
  float di = dinv[node];
  int deg = cnt[node]; if (deg > MAXD) deg = MAXD;

  int s_k = node; float c_k = 0.f;
  if (lane < deg){ s_k = slots[(size_t)node * MAXD + lane]; c_k = di * dinv[s_k]; }

  float a[8] = {0.f,0.f,0.f,0.f,0.f,0.f,0.f,0.f};
  auto acc8 = [&](uint4 v, float f){
    a[0]=fmaf(f,blo(v.x),a[0]); a[1]=fmaf(f,bhi(v.x),a[1]);
    a[2]=fmaf(f,blo(v.y),a[2]); a[3]=fmaf(f,bhi(v.y),a[3]);
    a[4]=fmaf(f,blo(v.z),a[4]); a[5]=fmaf(f,bhi(v.z),a[5]);
    a[6]=fmaf(f,blo(v.w),a[6]); a[7]=fmaf(f,bhi(v.w),a[7]);
  };

  for (int k0 = 0; k0 < deg; k0 += 16){
    int s0=__shfl(s_k,k0+g), s1=__shfl(s_k,k0+4+g), s2=__shfl(s_k,k0+8+g), s3=__shfl(s_k,k0+12+g);
    float f0=__shfl(c_k,k0+g), f1=__shfl(c_k,k0+4+g), f2=__shfl(c_k,k0+8+g), f3=__shfl(c_k,k0+12+g);
    uint4 v0 = *(const uint4*)(hml + (size_t)s0*128 + c*8);
    uint4 v1 = *(const uint4*)(hml + (size_t)s1*128 + c*8);
    uint4 v2 = *(const uint4*)(hml + (size_t)s2*128 + c*8);
    uint4 v3 = *(const uint4*)(hml + (size_t)s3*128 + c*8);
    acc8(v0,f0); acc8(v1,f1); acc8(v2,f2); acc8(v3,f3);
  }
  #pragma unroll
  for (int j = 0; j < 8; ++j){
    a[j] += __shfl_xor(a[j], 16);
    a[j] += __shfl_xor(a[j], 32);
  }
  uint4 sv = *(const uint4*)(hml + (size_t)node*128 + c*8);
  acc8(sv, di * di);
  // bias: c<8 -> mu channels c*8.., c>=8 -> logvar channels (c-8)*8..
  const float* bp = (c < 8) ? (bmu + c*8) : (blv + (c-8)*8);
  float4 bA = *(const float4*)bp;
  float4 bB = *(const float4*)(bp + 4);
  a[0]+=bA.x; a[1]+=bA.y; a[2]+=bA.z; a[3]+=bA.w;
  a[4]+=bB.x; a[5]+=bB.y; a[6]+=bB.z; a[7]+=bB.w;
  // swap mu<->logvar channel blocks (c ^ 8) so mu lanes see logvar
  float p[8];
  #pragma unroll
  for (int j = 0; j < 8; ++j) p[j] = __shfl_xor(a[j], 8);
  if (g == 0){
    if (c < 8){
      float4 eA = *(const float4*)(eps + (size_t)node*64 + c*8);
      float4 eB = *(const float4*)(eps + (size_t)node*64 + c*8 + 4);
      float z[8];
      z[0]=fmaf(eA.x, __expf(0.5f*p[0]), a[0]); z[1]=fmaf(eA.y, __expf(0.5f*p[1]), a[1]);
      z[2]=fmaf(eA.z, __expf(0.5f*p[2]), a[2]); z[3]=fmaf(eA.w, __expf(0.5f*p[3]), a[3]);
      z[4]=fmaf(eB.x, __expf(0.5f*p[4]), a[4]); z[5]=fmaf(eB.y, __expf(0.5f*p[5]), a[5]);
      z[6]=fmaf(eB.z, __expf(0.5f*p[6]), a[6]); z[7]=fmaf(eB.w, __expf(0.5f*p[7]), a[7]);
      *(float4*)(outz + (size_t)node*64 + c*8)     = make_float4(z[0],z[1],z[2],z[3]);
      *(float4*)(outz + (size_t)node*64 + c*8 + 4) = make_float4(z[4],z[5],z[6],z[7]);
      *(float4*)(outmu + (size_t)node*64 + c*8)     = make_float4(a[0],a[1],a[2],a[3]);
      *(float4*)(outmu + (size_t)node*64 + c*8 + 4) = make_float4(a[4],a[5],a[6],a[7]);
    } else {
      int cc = c - 8;
      *(float4*)(outlv + (size_t)node*64 + cc*8)     = make_float4(a[0],a[1],a[2],a[3]);
      *(float4*)(outlv + (size_t)node*64 + cc*8 + 4) = make_float4(a[4],a[5],a[6],a[7]);
    }
  }
}

// ---------- decoder: 16-lane group handles 2 edges; 4 independent float4 loads in flight ----------
__global__ __launch_bounds__(256) void k_dec(const int* __restrict__ src,
                                             const int* __restrict__ dst,
                                             const float* __restrict__ z,
                                             float* __restrict__ dec, int E){
  int t = blockIdx.x * 256 + threadIdx.x;
  int e0 = (t >> 4) * 2;
  if (e0 >= E) return;
  int sl = t & 15;
  int e1 = (e0 + 1 < E) ? e0 + 1 : e0;
  int s0 = src[e0], d0 = dst[e0];
  int s1 = src[e1], d1 = dst[e1];
  float4 a0 = *(const float4*)(z + (size_t)s0*64 + sl*4);
  float4 b0 = *(const float4*)(z + (size_t)d0*64 + sl*4);
  float4 a1 = *(const float4*)(z + (size_t)s1*64 + sl*4);
  float4 b1 = *(const float4*)(z + (size_t)d1*64 + sl*4);
  float t0 = a0.x*b0.x + a0.y*b0.y + a0.z*b0.z + a0.w*b0.w;
  float t1 = a1.x*b1.x + a1.y*b1.y + a1.z*b1.z + a1.w*b1.w;
  #pragma unroll
  for (int m = 1; m <= 8; m <<= 1){
    t0 += __shfl_xor(t0, m);
    t1 += __shfl_xor(t1, m);
  }
  if (sl == 0){
    if (e0 + 1 < E){
      *(float2*)(dec + e0) = make_float2(1.f/(1.f+__expf(-t0)), 1.f/(1.f+__expf(-t1)));
    } else {
      dec[e0] = 1.f/(1.f+__expf(-t0));
    }
  }
}

extern "C" void kernel_launch(void* const* d_in, const int* in_sizes, int n_in,
                              void* d_out, int out_size, void* d_ws, size_t ws_size,
                              hipStream_t stream){
  const float* x   = (const float*)d_in[0];
  const int*   ei  = (const int*)d_in[1];
  const float* eps = (const float*)d_in[2];
  const float* W1  = (const float*)d_in[3];
  const float* b1  = (const float*)d_in[4];
  const float* Wmu = (const float*)d_in[5];
  const float* bmu = (const float*)d_in[6];
  const float* Wlv = (const float*)d_in[7];
  const float* blv = (const float*)d_in[8];

  int N = in_sizes[0] / 256;
  int E = in_sizes[1] / 2;
  const int* src = ei;
  const int* dst = ei + E;

  char* w = (char*)d_ws;
  auto alloc = [&](size_t bytes) -> char* {
    char* p = w; w += (bytes + 255) & ~(size_t)255; return p;
  };
  int*            cnt   = (int*)            alloc((size_t)N * 4);
  float*          dinv  = (float*)          alloc((size_t)N * 4);
  int*            slots = (int*)            alloc((size_t)N * MAXD * 4);
  __hip_bfloat16* hlin  = (__hip_bfloat16*) alloc((size_t)N * 128 * 2);  // reused as hmulv
  __hip_bfloat16* h     = (__hip_bfloat16*) alloc((size_t)N * 128 * 2);
  __hip_bfloat16* W1T   = (__hip_bfloat16*) alloc((size_t)256 * 128 * 2);
  __hip_bfloat16* WcT   = (__hip_bfloat16*) alloc((size_t)128 * 128 * 2);

  float* oz   = (float*)d_out;
  float* omu  = oz  + (size_t)N * 64;
  float* olv  = omu + (size_t)N * 64;
  float* odec = olv + (size_t)N * 64;

  (void)hipMemsetAsync(cnt, 0, (size_t)N * 4, stream);

  k_count<<<(E + 255) / 256, 256, 0, stream>>>(src, dst, cnt, slots, E);
  k_dinv<<<(N + 255) / 256, 256, 0, stream>>>(cnt, dinv, N);

  k_tr<<<(256 * 128 + 255) / 256, 256, 0, stream>>>(W1, W1T, 256, 128);
  k_tr<<<(128 * 64 + 255) / 256, 256, 0, stream>>>(Wmu, WcT, 128, 64);
  k_tr<<<(128 * 64 + 255) / 256, 256, 0, stream>>>(Wlv, WcT + (size_t)64 * 128, 128, 64);

  k_gemm<true><<<(N + 63) / 64, 256, 0, stream>>>(x, W1T, hlin, N, 256);
  k_agg1<<<(N + 3) / 4, 256, 0, stream>>>(hlin, slots, cnt, dinv, b1, h, N);
  k_gemm<false><<<(N + 63) / 64, 256, 0, stream>>>(h, WcT, hlin, N, 128);
  k_agg2<<<(N + 3) / 4, 256, 0, stream>>>(hlin, slots, cnt, dinv, bmu, blv, eps,
                                          oz, omu, olv, N);

  int pairs = (E + 1) / 2;
  k_dec<<<((size_t)pairs * 16 + 255) / 256, 256, 0, stream>>>(src, dst, oz, odec, E);
}